// Round 4
// baseline (3965.135 us; speedup 1.0000x reference)
//
#include <hip/hip_runtime.h>

// 3-layer LSTM (B=1024, T=512, H=64), f16 MFMA, fp32 cell state.
// grid = 512 blocks x 2 batches; 768 threads = 12 waves = 3 layer-teams x 4.
// 2 blocks/CU (24 waves, 6/SIMD) so one block's barrier/latency stalls hide
// under the other block's issue.
// Software pipeline: team L computes layer L at t = s - L (skewed), all h
// state double-buffered in LDS -> 2 barriers per macro-step.
// Phase A: each team MFMAs its layer's gate preacts (weights in registers),
//          lanes with l4==0 write rows 0..1 (real batches) float4{i,f,g,o} to pre[].
// Phase C: waves 0..5 activate 1 cell/thread (Lc=wave>>1, b=wave&1, u=lane),
//          update fp32 c in-register, write f16 h to LDS.
// mfma_f32_16x16x32_f16: A row = lane&15 (batch), D col = lane&15 (unit),
//                        D row = (lane>>4)*4+reg (batch) -- verified R2/R3.

typedef __attribute__((ext_vector_type(8))) _Float16 half8;
typedef __attribute__((ext_vector_type(4))) _Float16 half4;
typedef __attribute__((ext_vector_type(4))) float floatx4;

static constexpr int T_STEPS = 512;

#define NL2E  (-1.4426950408889634f)   // -log2(e)
#define N2L2E (-2.8853900817779268f)   // -2*log2(e)

// LDS: "cr" rows of 256B = [16 slots][16B], slot XOR-swizzled by (cr&7).
// CR_X  : [2 buf][4 chunks]  (x frags, k=0..31, 24 real + 8 zero pad)
// CR_Hl : [2 buf][8 chunks]  (h frags, 64 units)
// A-frag batch rows 2..15 stay zero forever (zero-init, never written).
#define CR_X   0
#define CR_H0  8
#define CR_H1  24
#define CR_H2  40
#define CR_TOT 56
#define PRE_OFF  (CR_TOT * 256)            // float pre[3][128 cells][4 gates]
#define SM_BYTES (PRE_OFF + 3 * 128 * 4 * 4)

__device__ __forceinline__ int lds_off(int cr, int inner) {
    return (cr * 16 + (inner ^ (cr & 7))) * 16;
}

__device__ __forceinline__ floatx4 mfma16(half8 a, half8 b, floatx4 c) {
    return __builtin_amdgcn_mfma_f32_16x16x32_f16(a, b, c, 0, 0, 0);
}

// sig2(a) = 1/(1+2^a); caller pre-scales arg by -log2(e) (and bias folded).
__device__ __forceinline__ float sig2(float a) {
    return __builtin_amdgcn_rcpf(1.0f + __builtin_amdgcn_exp2f(a));
}

__device__ __forceinline__ half8 cvt8(const float* src) {
    float4 v0 = *(const float4*)(src);
    float4 v1 = *(const float4*)(src + 4);
    half8 h;
    h[0] = (_Float16)v0.x; h[1] = (_Float16)v0.y;
    h[2] = (_Float16)v0.z; h[3] = (_Float16)v0.w;
    h[4] = (_Float16)v1.x; h[5] = (_Float16)v1.y;
    h[6] = (_Float16)v1.z; h[7] = (_Float16)v1.w;
    return h;
}

__global__ __launch_bounds__(768, 6) void lstm3_pipe(
    const float* __restrict__ x,
    const float* __restrict__ w_ih0, const float* __restrict__ w_hh0,
    const float* __restrict__ b_ih0, const float* __restrict__ b_hh0,
    const float* __restrict__ w_ih1, const float* __restrict__ w_hh1,
    const float* __restrict__ b_ih1, const float* __restrict__ b_hh1,
    const float* __restrict__ w_ih2, const float* __restrict__ w_hh2,
    const float* __restrict__ b_ih2, const float* __restrict__ b_hh2,
    const float* __restrict__ w_lin, const float* __restrict__ b_lin,
    float* __restrict__ out)
{
    __shared__ __align__(16) char sm[SM_BYTES];
    float* pre = (float*)(sm + PRE_OFF);

    const int tid  = threadIdx.x;
    const int lane = tid & 63;
    const int wave = tid >> 6;       // 0..11
    const int L    = wave >> 2;      // MFMA team / layer 0..2
    const int w    = wave & 3;       // wave within team (= unit group)
    const int l15  = lane & 15;
    const int l4   = lane >> 4;
    const int b0   = blockIdx.x * 2; // global batch base (2 per block)

    // ---- zero x + h frag regions (rows 2..15 must stay zero) ----
    for (int i = tid; i < CR_TOT * 16; i += 768)
        *(floatx4*)(&sm[i * 16]) = floatx4{0.f, 0.f, 0.f, 0.f};

    // ---- per-team parameter pointers (phase A role) ----
    const float* wi = (L == 0) ? w_ih0 : (L == 1 ? w_ih1 : w_ih2);
    const float* wh = (L == 0) ? w_hh0 : (L == 1 ? w_hh1 : w_hh2);
    const int hbase = (L == 0) ? CR_H0 : (L == 1 ? CR_H1 : CR_H2);
    const int pbase = (L == 0) ? CR_X  : (L == 1 ? CR_H0 : CR_H1);

    // ---- register-resident B frags for THIS team's layer ----
    // B operand: lane&15 = gate col, lane>>4 = k-subchunk. K-axis:
    //  L=0: [x(24)+pad(8) | h0(64)] -> 3 k-groups;  L>=1: [h_prev(64)|h_own(64)] -> 4.
    half8 wf[4][4];
#pragma unroll
    for (int tt = 0; tt < 4; ++tt) {
        const int g = tt * 64 + w * 16 + l15;
        if (L == 0) {
            half8 z;
#pragma unroll
            for (int j = 0; j < 8; ++j) z[j] = (_Float16)0.f;
            wf[tt][0] = (l4 < 3) ? cvt8(w_ih0 + g * 24 + l4 * 8) : z;
            wf[tt][1] = cvt8(w_hh0 + g * 64 + l4 * 8);
            wf[tt][2] = cvt8(w_hh0 + g * 64 + 32 + l4 * 8);
            wf[tt][3] = z;   // unused
        } else {
            wf[tt][0] = cvt8(wi + g * 64 + l4 * 8);
            wf[tt][1] = cvt8(wi + g * 64 + 32 + l4 * 8);
            wf[tt][2] = cvt8(wh + g * 64 + l4 * 8);
            wf[tt][3] = cvt8(wh + g * 64 + 32 + l4 * 8);
        }
    }

    // ---- phase-C role: cell (Lc = wave>>1, bc = wave&1, u = lane), waves 0..5 ----
    const int Lc = wave >> 1;
    const int bc = wave & 1;
    const bool has_cell = (wave < 6);
    float bs[4];
    if (has_cell) {
        const float* bi_c = (Lc == 0) ? b_ih0 : (Lc == 1 ? b_ih1 : b_ih2);
        const float* bh_c = (Lc == 0) ? b_hh0 : (Lc == 1 ? b_hh1 : b_hh2);
#pragma unroll
        for (int tt = 0; tt < 4; ++tt) {
            float sc = (tt == 2) ? N2L2E : NL2E;
            bs[tt] = sc * (bi_c[tt * 64 + lane] + bh_c[tt * 64 + lane]);
        }
    }
    const int hbase_c = (Lc == 0) ? CR_H0 : (Lc == 1 ? CR_H1 : CR_H2);
    float cst = 0.0f;

    // ---- stage x(t=0) into x buffer 0 ----
    const int xb = tid / 6, xf = tid % 6;   // batch row, float4 index (tid<12)
    if (tid < 12) {
        float4 v = *(const float4*)(x + ((long)(b0 + xb) * T_STEPS + 0) * 24 + xf * 4);
        half4 hv; hv[0] = (_Float16)v.x; hv[1] = (_Float16)v.y;
                  hv[2] = (_Float16)v.z; hv[3] = (_Float16)v.w;
        *(half4*)(&sm[lds_off(CR_X + (xf >> 1), xb) + (xf & 1) * 8]) = hv;
    }
    __syncthreads();

    for (int s = 0; s < T_STEPS + 2; ++s) {
        const int t = s - L;
        const bool active = (t >= 0) && (t < T_STEPS);
        const int par = t & 1;

        // ---- x(s+1) prefetch issue (lands in LDS at end of phase C) ----
        float4 xpre;
        const bool do_x = (tid < 12) && (s + 1 < T_STEPS);
        if (do_x)
            xpre = *(const float4*)(x + ((long)(b0 + xb) * T_STEPS + (s + 1)) * 24 + xf * 4);

        // =============== phase A: MFMA gate preacts -> pre[] ===============
        if (active) {
            floatx4 acc[4];
            if (L == 0) {
                half8 aX  = *(const half8*)(&sm[lds_off(CR_X + par * 4 + l4, l15)]);
                half8 aP0 = *(const half8*)(&sm[lds_off(CR_H0 + (par ^ 1) * 8 + l4, l15)]);
                half8 aP1 = *(const half8*)(&sm[lds_off(CR_H0 + (par ^ 1) * 8 + 4 + l4, l15)]);
#pragma unroll
                for (int tt = 0; tt < 4; ++tt) {
#pragma unroll
                    for (int r = 0; r < 4; ++r) acc[tt][r] = 0.0f;
                    acc[tt] = mfma16(aX,  wf[tt][0], acc[tt]);
                    acc[tt] = mfma16(aP0, wf[tt][1], acc[tt]);
                    acc[tt] = mfma16(aP1, wf[tt][2], acc[tt]);
                }
            } else {
                half8 aI0 = *(const half8*)(&sm[lds_off(pbase + par * 8 + l4, l15)]);
                half8 aI1 = *(const half8*)(&sm[lds_off(pbase + par * 8 + 4 + l4, l15)]);
                half8 aO0 = *(const half8*)(&sm[lds_off(hbase + (par ^ 1) * 8 + l4, l15)]);
                half8 aO1 = *(const half8*)(&sm[lds_off(hbase + (par ^ 1) * 8 + 4 + l4, l15)]);
#pragma unroll
                for (int tt = 0; tt < 4; ++tt) {
#pragma unroll
                    for (int r = 0; r < 4; ++r) acc[tt][r] = 0.0f;
                    acc[tt] = mfma16(aI0, wf[tt][0], acc[tt]);
                    acc[tt] = mfma16(aI1, wf[tt][1], acc[tt]);
                    acc[tt] = mfma16(aO0, wf[tt][2], acc[tt]);
                    acc[tt] = mfma16(aO1, wf[tt][3], acc[tt]);
                }
            }
            if (l4 == 0) {   // D rows 0..1 = real batches
#pragma unroll
                for (int r = 0; r < 2; ++r) {
                    floatx4 pv;
                    pv[0] = acc[0][r]; pv[1] = acc[1][r];
                    pv[2] = acc[2][r]; pv[3] = acc[3][r];
                    *(floatx4*)(&pre[(L * 128 + r * 64 + w * 16 + l15) * 4]) = pv;
                }
            }
        }
        __syncthreads();   // B: pre[] visible

        // ======= phase C: 1 cell per thread: activate, update c, write h ====
        if (has_cell) {
            const int tc = s - Lc;
            if (tc >= 0 && tc < T_STEPS) {
                const floatx4 p = *(const floatx4*)(&pre[(Lc * 128 + bc * 64 + lane) * 4]);
                float ig = sig2(fmaf(p[0], NL2E,  bs[0]));
                float fg = sig2(fmaf(p[1], NL2E,  bs[1]));
                float gg = fmaf(2.0f, sig2(fmaf(p[2], N2L2E, bs[2])), -1.0f);
                float og = sig2(fmaf(p[3], NL2E,  bs[3]));
                cst = fmaf(fg, cst, ig * gg);
                float hv = og * fmaf(2.0f, sig2(cst * N2L2E), -1.0f);
                const int c = lane >> 3;
                *(_Float16*)(&sm[lds_off(hbase_c + (tc & 1) * 8 + c, bc) + (lane & 7) * 2]) =
                    (_Float16)hv;
            }
        }
        if (do_x) {
            half4 hv; hv[0] = (_Float16)xpre.x; hv[1] = (_Float16)xpre.y;
                      hv[2] = (_Float16)xpre.z; hv[3] = (_Float16)xpre.w;
            *(half4*)(&sm[lds_off(CR_X + ((s + 1) & 1) * 4 + (xf >> 1), xb) + (xf & 1) * 8]) = hv;
        }
        __syncthreads();   // D: h(t), x(s+1) visible
    }

    // ---- final linear: out[b,o] = h2(511) . w_lin[o,:] + b_lin[o] ----
    if (tid < 8) {
        const int bb = tid >> 2, o = tid & 3;
        const int hb = CR_H2 + ((T_STEPS - 1) & 1) * 8;
        float acc = b_lin[o];
#pragma unroll
        for (int k = 0; k < 64; ++k) {
            _Float16 hv = *(const _Float16*)(&sm[lds_off(hb + (k >> 3), bb) + (k & 7) * 2]);
            acc = fmaf((float)hv, w_lin[o * 64 + k], acc);
        }
        out[(b0 + bb) * 4 + o] = acc;
    }
}

extern "C" void kernel_launch(void* const* d_in, const int* in_sizes, int n_in,
                              void* d_out, int out_size, void* d_ws, size_t ws_size,
                              hipStream_t stream) {
    const float* x     = (const float*)d_in[0];
    const float* w_ih0 = (const float*)d_in[1];
    const float* w_hh0 = (const float*)d_in[2];
    const float* b_ih0 = (const float*)d_in[3];
    const float* b_hh0 = (const float*)d_in[4];
    const float* w_ih1 = (const float*)d_in[5];
    const float* w_hh1 = (const float*)d_in[6];
    const float* b_ih1 = (const float*)d_in[7];
    const float* b_hh1 = (const float*)d_in[8];
    const float* w_ih2 = (const float*)d_in[9];
    const float* w_hh2 = (const float*)d_in[10];
    const float* b_ih2 = (const float*)d_in[11];
    const float* b_hh2 = (const float*)d_in[12];
    const float* w_lin = (const float*)d_in[13];
    const float* b_lin = (const float*)d_in[14];

    lstm3_pipe<<<dim3(512), dim3(768), 0, stream>>>(
        x, w_ih0, w_hh0, b_ih0, b_hh0,
        w_ih1, w_hh1, b_ih1, b_hh1,
        w_ih2, w_hh2, b_ih2, b_hh2,
        w_lin, b_lin, (float*)d_out);
}

// Round 5
// 339.979 us; speedup vs baseline: 11.6629x; 11.6629x over previous
//
#include <hip/hip_runtime.h>

// 3-layer LSTM (B=1024, T=512, H=64), f16 MFMA, fp32 cell state.
// grid = 256 blocks x 4 batches; 768 threads = 12 waves = 3 layer-teams x 4.
// Team L computes layer L at t = s - L (skewed pipeline), ONE barrier/step.
//
// Key trick: A-fragment reads use slot = l15>>2 (4-way same-address broadcast,
// free) so A-row m carries batch m>>2. Then D-row 4*l4+r = batch l4, i.e.
// acc[tt][0] on lane (l4,l15) IS the preactivation of cell (batch=l4,
// unit=w*16+l15): activation runs on all 64 lanes, one cell per lane, with
// no LDS redistribution and no second barrier. Cell state = 1 VGPR/lane.
// mfma_f32_16x16x32_f16: A row = lane&15, k-chunk = lane>>4; D col = lane&15,
// D row = (lane>>4)*4+reg -- layout verified R2-R4.

typedef __attribute__((ext_vector_type(8))) _Float16 half8;
typedef __attribute__((ext_vector_type(4))) _Float16 half4;
typedef __attribute__((ext_vector_type(4))) float floatx4;

static constexpr int T_STEPS = 512;

#define NL2E  (-1.4426950408889634f)   // -log2(e)
#define N2L2E (-2.8853900817779268f)   // -2*log2(e)

// LDS: "cr" rows of 256B = [16 slots][16B], slot XOR-swizzled by (cr&7).
// CR_X  : [2 buf][4 chunks]  (x frags, k=0..31, 24 real + 8 zero pad)
// CR_Hl : [2 buf][8 chunks]  (h frags, 64 units)
// Slots 0..3 = batches; slots 4..15 unused (A-reads broadcast slots 0..3).
#define CR_X   0
#define CR_H0  8
#define CR_H1  24
#define CR_H2  40
#define CR_TOT 56
#define SM_BYTES (CR_TOT * 256)        // 14336 B

__device__ __forceinline__ int lds_off(int cr, int inner) {
    return (cr * 16 + (inner ^ (cr & 7))) * 16;
}

__device__ __forceinline__ floatx4 mfma16(half8 a, half8 b, floatx4 c) {
    return __builtin_amdgcn_mfma_f32_16x16x32_f16(a, b, c, 0, 0, 0);
}

// sig2(a) = 1/(1+2^a); caller pre-scales arg by -log2(e) (bias folded).
__device__ __forceinline__ float sig2(float a) {
    return __builtin_amdgcn_rcpf(1.0f + __builtin_amdgcn_exp2f(a));
}

__device__ __forceinline__ half8 cvt8(const float* src) {
    float4 v0 = *(const float4*)(src);
    float4 v1 = *(const float4*)(src + 4);
    half8 h;
    h[0] = (_Float16)v0.x; h[1] = (_Float16)v0.y;
    h[2] = (_Float16)v0.z; h[3] = (_Float16)v0.w;
    h[4] = (_Float16)v1.x; h[5] = (_Float16)v1.y;
    h[6] = (_Float16)v1.z; h[7] = (_Float16)v1.w;
    return h;
}

__global__ __launch_bounds__(768, 3) void lstm3_fused(
    const float* __restrict__ x,
    const float* __restrict__ w_ih0, const float* __restrict__ w_hh0,
    const float* __restrict__ b_ih0, const float* __restrict__ b_hh0,
    const float* __restrict__ w_ih1, const float* __restrict__ w_hh1,
    const float* __restrict__ b_ih1, const float* __restrict__ b_hh1,
    const float* __restrict__ w_ih2, const float* __restrict__ w_hh2,
    const float* __restrict__ b_ih2, const float* __restrict__ b_hh2,
    const float* __restrict__ w_lin, const float* __restrict__ b_lin,
    float* __restrict__ out)
{
    __shared__ __align__(16) char sm[SM_BYTES];

    const int tid  = threadIdx.x;
    const int lane = tid & 63;
    const int wave = tid >> 6;       // 0..11
    const int L    = wave >> 2;      // layer team 0..2
    const int w    = wave & 3;       // unit group within team
    const int l15  = lane & 15;
    const int l4   = lane >> 4;      // = this lane's BATCH for activation
    const int b0   = blockIdx.x * 4; // global batch base (4 per block)
    const int u    = w * 16 + l15;   // this lane's hidden unit

    // ---- zero x + h frag regions ----
    for (int i = tid; i < CR_TOT * 16; i += 768)
        *(floatx4*)(&sm[i * 16]) = floatx4{0.f, 0.f, 0.f, 0.f};

    // ---- per-team parameter pointers ----
    const float* wi = (L == 0) ? w_ih0 : (L == 1 ? w_ih1 : w_ih2);
    const float* wh = (L == 0) ? w_hh0 : (L == 1 ? w_hh1 : w_hh2);
    const float* bi = (L == 0) ? b_ih0 : (L == 1 ? b_ih1 : b_ih2);
    const float* bh = (L == 0) ? b_hh0 : (L == 1 ? b_hh1 : b_hh2);
    const int hbase = (L == 0) ? CR_H0 : (L == 1 ? CR_H1 : CR_H2);
    const int pbase = (L == 0) ? CR_X  : (L == 1 ? CR_H0 : CR_H1);

    // ---- register-resident B frags (weights) for THIS team's layer ----
    // K-axis: L=0: [x(24)+pad(8) | h0(64)] -> 3 groups; L>=1: [h_prev|h_own] -> 4.
    half8 wf[4][4];
#pragma unroll
    for (int tt = 0; tt < 4; ++tt) {
        const int g = tt * 64 + u;
        if (L == 0) {
            half8 z;
#pragma unroll
            for (int j = 0; j < 8; ++j) z[j] = (_Float16)0.f;
            wf[tt][0] = (l4 < 3) ? cvt8(w_ih0 + g * 24 + l4 * 8) : z;
            wf[tt][1] = cvt8(w_hh0 + g * 64 + l4 * 8);
            wf[tt][2] = cvt8(w_hh0 + g * 64 + 32 + l4 * 8);
            wf[tt][3] = z;   // unused
        } else {
            wf[tt][0] = cvt8(wi + g * 64 + l4 * 8);
            wf[tt][1] = cvt8(wi + g * 64 + 32 + l4 * 8);
            wf[tt][2] = cvt8(wh + g * 64 + l4 * 8);
            wf[tt][3] = cvt8(wh + g * 64 + 32 + l4 * 8);
        }
    }

    // ---- per-lane activation constants: cell (L, batch=l4, unit=u) ----
    float bs[4];
#pragma unroll
    for (int tt = 0; tt < 4; ++tt) {
        float sc = (tt == 2) ? N2L2E : NL2E;
        bs[tt] = sc * (bi[tt * 64 + u] + bh[tt * 64 + u]);
    }
    float cst = 0.0f;    // fp32 cell state of (batch l4, unit u, layer L)

    // ---- stage x(t=0) into x buffer 0 ----
    const int xb = tid / 6, xf = tid % 6;   // batch, float4 index (tid<24)
    if (tid < 24) {
        float4 v = *(const float4*)(x + ((long)(b0 + xb) * T_STEPS + 0) * 24 + xf * 4);
        half4 hv; hv[0] = (_Float16)v.x; hv[1] = (_Float16)v.y;
                  hv[2] = (_Float16)v.z; hv[3] = (_Float16)v.w;
        *(half4*)(&sm[lds_off(CR_X + (xf >> 1), xb) + (xf & 1) * 8]) = hv;
    }
    __syncthreads();

    for (int s = 0; s < T_STEPS + 2; ++s) {
        const int t = s - L;
        const bool active = (t >= 0) && (t < T_STEPS);
        const int par = t & 1;

        // ---- x(s+1) prefetch issue (LDS commit at end of step) ----
        float4 xpre;
        const bool do_x = (tid < 24) && (s + 1 < T_STEPS);
        if (do_x)
            xpre = *(const float4*)(x + ((long)(b0 + xb) * T_STEPS + (s + 1)) * 24 + xf * 4);

        if (active) {
            // ---- MFMA gate preacts; A slots broadcast so row m = batch m>>2 ----
            const int sl = l15 >> 2;
            floatx4 acc[4];
            if (L == 0) {
                half8 aX  = *(const half8*)(&sm[lds_off(CR_X + par * 4 + l4, sl)]);
                half8 aP0 = *(const half8*)(&sm[lds_off(CR_H0 + (par ^ 1) * 8 + l4, sl)]);
                half8 aP1 = *(const half8*)(&sm[lds_off(CR_H0 + (par ^ 1) * 8 + 4 + l4, sl)]);
#pragma unroll
                for (int tt = 0; tt < 4; ++tt) {
#pragma unroll
                    for (int r = 0; r < 4; ++r) acc[tt][r] = 0.0f;
                    acc[tt] = mfma16(aX,  wf[tt][0], acc[tt]);
                    acc[tt] = mfma16(aP0, wf[tt][1], acc[tt]);
                    acc[tt] = mfma16(aP1, wf[tt][2], acc[tt]);
                }
            } else {
                half8 aI0 = *(const half8*)(&sm[lds_off(pbase + par * 8 + l4, sl)]);
                half8 aI1 = *(const half8*)(&sm[lds_off(pbase + par * 8 + 4 + l4, sl)]);
                half8 aO0 = *(const half8*)(&sm[lds_off(hbase + (par ^ 1) * 8 + l4, sl)]);
                half8 aO1 = *(const half8*)(&sm[lds_off(hbase + (par ^ 1) * 8 + 4 + l4, sl)]);
#pragma unroll
                for (int tt = 0; tt < 4; ++tt) {
#pragma unroll
                    for (int r = 0; r < 4; ++r) acc[tt][r] = 0.0f;
                    acc[tt] = mfma16(aI0, wf[tt][0], acc[tt]);
                    acc[tt] = mfma16(aI1, wf[tt][1], acc[tt]);
                    acc[tt] = mfma16(aO0, wf[tt][2], acc[tt]);
                    acc[tt] = mfma16(aO1, wf[tt][3], acc[tt]);
                }
            }

            // ---- activation: 1 cell/lane (batch=l4, unit=u), in-register ----
            float ig = sig2(fmaf(acc[0][0], NL2E,  bs[0]));
            float fg = sig2(fmaf(acc[1][0], NL2E,  bs[1]));
            float gg = fmaf(2.0f, sig2(fmaf(acc[2][0], N2L2E, bs[2])), -1.0f);
            float og = sig2(fmaf(acc[3][0], NL2E,  bs[3]));
            cst = fmaf(fg, cst, ig * gg);
            float hv = og * fmaf(2.0f, sig2(cst * N2L2E), -1.0f);
            *(_Float16*)(&sm[lds_off(hbase + par * 8 + (u >> 3), l4) + (u & 7) * 2]) =
                (_Float16)hv;
        }
        if (do_x) {
            half4 hv; hv[0] = (_Float16)xpre.x; hv[1] = (_Float16)xpre.y;
                      hv[2] = (_Float16)xpre.z; hv[3] = (_Float16)xpre.w;
            *(half4*)(&sm[lds_off(CR_X + ((s + 1) & 1) * 4 + (xf >> 1), xb) + (xf & 1) * 8]) = hv;
        }
        __syncthreads();   // h(t), x(s+1) visible; next step reads other buffers
    }

    // ---- final linear: out[b,o] = h2(511) . w_lin[o,:] + b_lin[o] ----
    if (tid < 16) {
        const int bb = tid >> 2, o = tid & 3;
        const int hb = CR_H2 + ((T_STEPS - 1) & 1) * 8;
        float acc = b_lin[o];
#pragma unroll
        for (int k = 0; k < 64; ++k) {
            _Float16 hv = *(const _Float16*)(&sm[lds_off(hb + (k >> 3), bb) + (k & 7) * 2]);
            acc = fmaf((float)hv, w_lin[o * 64 + k], acc);
        }
        out[(b0 + bb) * 4 + o] = acc;
    }
}

extern "C" void kernel_launch(void* const* d_in, const int* in_sizes, int n_in,
                              void* d_out, int out_size, void* d_ws, size_t ws_size,
                              hipStream_t stream) {
    const float* x     = (const float*)d_in[0];
    const float* w_ih0 = (const float*)d_in[1];
    const float* w_hh0 = (const float*)d_in[2];
    const float* b_ih0 = (const float*)d_in[3];
    const float* b_hh0 = (const float*)d_in[4];
    const float* w_ih1 = (const float*)d_in[5];
    const float* w_hh1 = (const float*)d_in[6];
    const float* b_ih1 = (const float*)d_in[7];
    const float* b_hh1 = (const float*)d_in[8];
    const float* w_ih2 = (const float*)d_in[9];
    const float* w_hh2 = (const float*)d_in[10];
    const float* b_ih2 = (const float*)d_in[11];
    const float* b_hh2 = (const float*)d_in[12];
    const float* w_lin = (const float*)d_in[13];
    const float* b_lin = (const float*)d_in[14];

    lstm3_fused<<<dim3(256), dim3(768), 0, stream>>>(
        x, w_ih0, w_hh0, b_ih0, b_hh0,
        w_ih1, w_hh1, b_ih1, b_hh1,
        w_ih2, w_hh2, b_ih2, b_hh2,
        w_lin, b_lin, (float*)d_out);
}

// Round 6
// 301.221 us; speedup vs baseline: 13.1635x; 1.1287x over previous
//
#include <hip/hip_runtime.h>

// 3-layer LSTM (B=1024, T=512, H=64), f16 MFMA, fp32 cell state.
// grid = 256 blocks x 4 batches; 768 threads = 12 waves = 3 layer-teams x 4.
// Team L computes layer L at t = s - L (skewed pipeline), ONE barrier/step.
//
// A-fragment reads use slot = l15>>2 (4-way same-address broadcast) so
// D-row 4*l4+r = batch l4: acc[tt][0] on lane (l4,l15) IS the preact of cell
// (batch=l4, unit=w*16+l15) -> activation fully lane-local, no second barrier.
//
// R6 changes vs R5:
//  * parity swizzle slot^=(cr&1)<<2: even rows use banks 0-15, odd rows
//    16-31 -> every access <=2-way (R5's cr&7 swizzle crammed all A-read
//    lines into banks 0-15: 2.6e7 conflict cycles).
//  * s-loop unrolled x2, all LDS addresses precomputed per-parity and
//    hoisted (parity selects are loop-invariant).
//  * bias rides as the MFMA C-input (no acc zero-init movs).
//  * s_setprio(1) around the MFMA cluster.
// mfma_f32_16x16x32_f16: A row = lane&15, k-chunk = lane>>4; D col = lane&15,
// D row = (lane>>4)*4+reg -- layout verified R2-R5.

typedef __attribute__((ext_vector_type(8))) _Float16 half8;
typedef __attribute__((ext_vector_type(4))) _Float16 half4;
typedef __attribute__((ext_vector_type(4))) float floatx4;

static constexpr int T_STEPS = 512;

#define NL2E  (-1.4426950408889634f)   // -log2(e)
#define N2L2E (-2.8853900817779268f)   // -2*log2(e)

// LDS: "cr" rows of 256B = [16 slots][16B]; slot ^= (cr&1)<<2.
// CR_X  : [2 buf][4 chunks]  (x frags, k=0..31, 24 real + 8 zero pad)
// CR_Hl : [2 buf][8 chunks]  (h frags, 64 units); slots 0..3 = batches.
#define CR_X   0
#define CR_H0  8
#define CR_H1  24
#define CR_H2  40
#define CR_TOT 56
#define SM_BYTES (CR_TOT * 256)        // 14336 B

__device__ __forceinline__ int lds_off(int cr, int slot) {
    return (cr * 16 + (slot ^ ((cr & 1) << 2))) * 16;
}

__device__ __forceinline__ floatx4 mfma16(half8 a, half8 b, floatx4 c) {
    return __builtin_amdgcn_mfma_f32_16x16x32_f16(a, b, c, 0, 0, 0);
}

// sig2(a) = 1/(1+2^a);  sigmoid(x) = sig2(x*NL2E), tanh(x) = 2*sig2(x*N2L2E)-1
__device__ __forceinline__ float sig2(float a) {
    return __builtin_amdgcn_rcpf(1.0f + __builtin_amdgcn_exp2f(a));
}

__device__ __forceinline__ half8 cvt8(const float* src) {
    float4 v0 = *(const float4*)(src);
    float4 v1 = *(const float4*)(src + 4);
    half8 h;
    h[0] = (_Float16)v0.x; h[1] = (_Float16)v0.y;
    h[2] = (_Float16)v0.z; h[3] = (_Float16)v0.w;
    h[4] = (_Float16)v1.x; h[5] = (_Float16)v1.y;
    h[6] = (_Float16)v1.z; h[7] = (_Float16)v1.w;
    return h;
}

__global__ __launch_bounds__(768, 3) void lstm3_fused(
    const float* __restrict__ x,
    const float* __restrict__ w_ih0, const float* __restrict__ w_hh0,
    const float* __restrict__ b_ih0, const float* __restrict__ b_hh0,
    const float* __restrict__ w_ih1, const float* __restrict__ w_hh1,
    const float* __restrict__ b_ih1, const float* __restrict__ b_hh1,
    const float* __restrict__ w_ih2, const float* __restrict__ w_hh2,
    const float* __restrict__ b_ih2, const float* __restrict__ b_hh2,
    const float* __restrict__ w_lin, const float* __restrict__ b_lin,
    float* __restrict__ out)
{
    __shared__ __align__(16) char sm[SM_BYTES];

    const int tid  = threadIdx.x;
    const int lane = tid & 63;
    const int wave = tid >> 6;       // 0..11
    const int L    = wave >> 2;      // layer team 0..2
    const int w    = wave & 3;       // unit group within team
    const int l15  = lane & 15;
    const int l4   = lane >> 4;      // = this lane's BATCH
    const int b0   = blockIdx.x * 4; // global batch base (4 per block)
    const int u    = w * 16 + l15;   // this lane's hidden unit
    const int sl   = l15 >> 2;       // broadcast A slot

    // ---- zero x + h frag regions ----
    for (int i = tid; i < CR_TOT * 16; i += 768)
        *(floatx4*)(&sm[i * 16]) = floatx4{0.f, 0.f, 0.f, 0.f};

    // ---- per-team parameter pointers ----
    const float* wi = (L == 0) ? w_ih0 : (L == 1 ? w_ih1 : w_ih2);
    const float* wh = (L == 0) ? w_hh0 : (L == 1 ? w_hh1 : w_hh2);
    const float* bi = (L == 0) ? b_ih0 : (L == 1 ? b_ih1 : b_ih2);
    const float* bh = (L == 0) ? b_hh0 : (L == 1 ? b_hh1 : b_hh2);
    const int hbase = (L == 0) ? CR_H0 : (L == 1 ? CR_H1 : CR_H2);
    const int pbase = (L == 0) ? CR_X  : (L == 1 ? CR_H0 : CR_H1);

    // ---- register-resident B frags (weights) ----
    half8 wf[4][4];
#pragma unroll
    for (int tt = 0; tt < 4; ++tt) {
        const int g = tt * 64 + u;
        if (L == 0) {
            half8 z;
#pragma unroll
            for (int j = 0; j < 8; ++j) z[j] = (_Float16)0.f;
            wf[tt][0] = (l4 < 3) ? cvt8(w_ih0 + g * 24 + l4 * 8) : z;
            wf[tt][1] = cvt8(w_hh0 + g * 64 + l4 * 8);
            wf[tt][2] = cvt8(w_hh0 + g * 64 + 32 + l4 * 8);
            wf[tt][3] = z;   // unused
        } else {
            wf[tt][0] = cvt8(wi + g * 64 + l4 * 8);
            wf[tt][1] = cvt8(wi + g * 64 + 32 + l4 * 8);
            wf[tt][2] = cvt8(wh + g * 64 + l4 * 8);
            wf[tt][3] = cvt8(wh + g * 64 + 32 + l4 * 8);
        }
    }

    // ---- raw bias as MFMA C-input (same for all 4 acc rows) ----
    floatx4 bv[4];
#pragma unroll
    for (int tt = 0; tt < 4; ++tt) {
        float b = bi[tt * 64 + u] + bh[tt * 64 + u];
        bv[tt][0] = b; bv[tt][1] = b; bv[tt][2] = b; bv[tt][3] = b;
    }
    float cst = 0.0f;    // fp32 cell state of (batch l4, unit u, layer L)

    // ---- precomputed LDS byte addresses, both parities ----
    int ra0[4], ra1[4];
    if (L == 0) {
        ra0[0] = lds_off(CR_X + 0 + l4, sl);
        ra0[1] = lds_off(CR_H0 + 8 + l4, sl);
        ra0[2] = lds_off(CR_H0 + 12 + l4, sl);
        ra0[3] = 0;
        ra1[0] = lds_off(CR_X + 4 + l4, sl);
        ra1[1] = lds_off(CR_H0 + 0 + l4, sl);
        ra1[2] = lds_off(CR_H0 + 4 + l4, sl);
        ra1[3] = 0;
    } else {
        ra0[0] = lds_off(pbase + 0 + l4, sl);
        ra0[1] = lds_off(pbase + 4 + l4, sl);
        ra0[2] = lds_off(hbase + 8 + l4, sl);
        ra0[3] = lds_off(hbase + 12 + l4, sl);
        ra1[0] = lds_off(pbase + 8 + l4, sl);
        ra1[1] = lds_off(pbase + 12 + l4, sl);
        ra1[2] = lds_off(hbase + 0 + l4, sl);
        ra1[3] = lds_off(hbase + 4 + l4, sl);
    }
    const int wr0 = lds_off(hbase + 0 + (u >> 3), l4) + (u & 7) * 2;
    const int wr1 = lds_off(hbase + 8 + (u >> 3), l4) + (u & 7) * 2;

    // parity selects (loop-invariant, hoisted): even-s body has par = L&1
    const int Lodd = L & 1;
    const int eA0 = Lodd ? ra1[0] : ra0[0], eA1 = Lodd ? ra1[1] : ra0[1];
    const int eA2 = Lodd ? ra1[2] : ra0[2], eA3 = Lodd ? ra1[3] : ra0[3];
    const int oA0 = Lodd ? ra0[0] : ra1[0], oA1 = Lodd ? ra0[1] : ra1[1];
    const int oA2 = Lodd ? ra0[2] : ra1[2], oA3 = Lodd ? ra0[3] : ra1[3];
    const int eWr = Lodd ? wr1 : wr0, oWr = Lodd ? wr0 : wr1;

    // ---- x staging: thread tid<24 owns (batch xb, float4 xf) ----
    const int xb = tid / 6, xf = tid % 6;
    const int xw0 = lds_off(CR_X + 0 + (xf >> 1), xb) + (xf & 1) * 8;
    const int xw1 = lds_off(CR_X + 4 + (xf >> 1), xb) + (xf & 1) * 8;
    const float* xg = x + ((long)(b0 + xb) * T_STEPS + 1) * 24 + xf * 4;
    if (tid < 24) {
        float4 v = *(const float4*)(x + ((long)(b0 + xb) * T_STEPS + 0) * 24 + xf * 4);
        half4 hv; hv[0] = (_Float16)v.x; hv[1] = (_Float16)v.y;
                  hv[2] = (_Float16)v.z; hv[3] = (_Float16)v.w;
        *(half4*)(&sm[xw0]) = hv;
    }
    __syncthreads();

    auto body = [&](int s, int A0, int A1, int A2, int A3, int WR, int XW) {
        const int t = s - L;
        const bool active = ((unsigned)t < (unsigned)T_STEPS);
        float4 xpre;
        const bool do_x = (tid < 24) && (s + 1 < T_STEPS);
        if (do_x) xpre = *(const float4*)xg;

        if (active) {
            floatx4 acc[4];
            __builtin_amdgcn_s_setprio(1);
            if (L == 0) {
                half8 aX  = *(const half8*)(&sm[A0]);
                half8 aP0 = *(const half8*)(&sm[A1]);
                half8 aP1 = *(const half8*)(&sm[A2]);
#pragma unroll
                for (int tt = 0; tt < 4; ++tt) {
                    acc[tt] = mfma16(aX,  wf[tt][0], bv[tt]);
                    acc[tt] = mfma16(aP0, wf[tt][1], acc[tt]);
                    acc[tt] = mfma16(aP1, wf[tt][2], acc[tt]);
                }
            } else {
                half8 aI0 = *(const half8*)(&sm[A0]);
                half8 aI1 = *(const half8*)(&sm[A1]);
                half8 aO0 = *(const half8*)(&sm[A2]);
                half8 aO1 = *(const half8*)(&sm[A3]);
#pragma unroll
                for (int tt = 0; tt < 4; ++tt) {
                    acc[tt] = mfma16(aI0, wf[tt][0], bv[tt]);
                    acc[tt] = mfma16(aI1, wf[tt][1], acc[tt]);
                    acc[tt] = mfma16(aO0, wf[tt][2], acc[tt]);
                    acc[tt] = mfma16(aO1, wf[tt][3], acc[tt]);
                }
            }
            __builtin_amdgcn_s_setprio(0);

            // activation: 1 cell/lane (batch=l4, unit=u); acc includes bias
            float ig = sig2(acc[0][0] * NL2E);
            float fg = sig2(acc[1][0] * NL2E);
            float gg = fmaf(2.0f, sig2(acc[2][0] * N2L2E), -1.0f);
            float og = sig2(acc[3][0] * NL2E);
            cst = fmaf(fg, cst, ig * gg);
            float hv = og * fmaf(2.0f, sig2(cst * N2L2E), -1.0f);
            *(_Float16*)(&sm[WR]) = (_Float16)hv;
        }
        if (do_x) {
            half4 hv; hv[0] = (_Float16)xpre.x; hv[1] = (_Float16)xpre.y;
                      hv[2] = (_Float16)xpre.z; hv[3] = (_Float16)xpre.w;
            *(half4*)(&sm[XW]) = hv;
        }
        xg += 24;
        __syncthreads();
    };

    for (int s = 0; s < T_STEPS + 2; s += 2) {
        body(s,     eA0, eA1, eA2, eA3, eWr, xw1);   // writes x(s+1) -> buf 1
        body(s + 1, oA0, oA1, oA2, oA3, oWr, xw0);   // writes x(s+2) -> buf 0
    }

    // ---- final linear: out[b,o] = h2(511) . w_lin[o,:] + b_lin[o] ----
    if (tid < 16) {
        const int bb = tid >> 2, o = tid & 3;
        const int hb = CR_H2 + ((T_STEPS - 1) & 1) * 8;
        float acc = b_lin[o];
#pragma unroll
        for (int k = 0; k < 64; ++k) {
            _Float16 hv = *(const _Float16*)(&sm[lds_off(hb + (k >> 3), bb) + (k & 7) * 2]);
            acc = fmaf((float)hv, w_lin[o * 64 + k], acc);
        }
        out[(b0 + bb) * 4 + o] = acc;
    }
}

extern "C" void kernel_launch(void* const* d_in, const int* in_sizes, int n_in,
                              void* d_out, int out_size, void* d_ws, size_t ws_size,
                              hipStream_t stream) {
    const float* x     = (const float*)d_in[0];
    const float* w_ih0 = (const float*)d_in[1];
    const float* w_hh0 = (const float*)d_in[2];
    const float* b_ih0 = (const float*)d_in[3];
    const float* b_hh0 = (const float*)d_in[4];
    const float* w_ih1 = (const float*)d_in[5];
    const float* w_hh1 = (const float*)d_in[6];
    const float* b_ih1 = (const float*)d_in[7];
    const float* b_hh1 = (const float*)d_in[8];
    const float* w_ih2 = (const float*)d_in[9];
    const float* w_hh2 = (const float*)d_in[10];
    const float* b_ih2 = (const float*)d_in[11];
    const float* b_hh2 = (const float*)d_in[12];
    const float* w_lin = (const float*)d_in[13];
    const float* b_lin = (const float*)d_in[14];

    lstm3_fused<<<dim3(256), dim3(768), 0, stream>>>(
        x, w_ih0, w_hh0, b_ih0, b_hh0,
        w_ih1, w_hh1, b_ih1, b_hh1,
        w_ih2, w_hh2, b_ih2, b_hh2,
        w_lin, b_lin, (float*)d_out);
}